// Round 3
// baseline (101.046 us; speedup 1.0000x reference)
//
#include <hip/hip_runtime.h>

#define GAT_ALPHA 0.2f
#define INV_N (1.0f / 2048.0f)

typedef float f32x4 __attribute__((ext_vector_type(4)));
typedef int   i32x4 __attribute__((ext_vector_type(4)));
typedef __bf16 bf16x8 __attribute__((ext_vector_type(8)));
typedef unsigned short us8 __attribute__((ext_vector_type(8)));

__device__ __forceinline__ unsigned short f2bf(float x) {
  union { float f; unsigned u; } v; v.f = x;
  unsigned r = v.u + 0x7FFFu + ((v.u >> 16) & 1u);   // RNE
  return (unsigned short)(r >> 16);
}
__device__ __forceinline__ bf16x8 as_bf16(us8 u) {
  union { us8 a; bf16x8 b; } c; c.a = u; return c.b;
}
__device__ __forceinline__ float lrelu(float x) {
  return fmaxf(x, 0.f) + GAT_ALPHA * fminf(x, 0.f);
}
__device__ __forceinline__ void lgkm_barrier() {
  asm volatile("s_waitcnt lgkmcnt(0)" ::: "memory");
  __builtin_amdgcn_s_barrier();
  __builtin_amdgcn_sched_barrier(0);
}

// ---------------- k0: Wh = h @ W (f32), s1/s2, WhT in bf16 [b][f][j] ----------------
__global__ __launch_bounds__(256)
void k0_wh(const float* __restrict__ h, const float* __restrict__ W,
           const float* __restrict__ a, unsigned short* __restrict__ WhT,
           float* __restrict__ s1g, float* __restrict__ s2g)
{
  __shared__ float h_s[64][132];
  __shared__ float W_s[128][64];
  __shared__ float wt_s[64][66];
  __shared__ float a_s[128];
  const int t = threadIdx.x;
  const int b = blockIdx.y;
  const int r0 = blockIdx.x * 64;

#pragma unroll
  for (int v = 0; v < 8; ++v) {
    int c = v * 256 + t;
    int k = c >> 4, fo = (c & 15) << 2;
    *(float4*)&W_s[k][fo] = *(const float4*)&W[k * 64 + fo];
  }
#pragma unroll
  for (int v = 0; v < 8; ++v) {
    int c = v * 256 + t;
    int r = c >> 5, ko = (c & 31) << 2;
    *(float4*)&h_s[r][ko] = *(const float4*)&h[((size_t)(b * 2048 + r0 + r)) * 128 + ko];
  }
  if (t < 128) a_s[t] = a[t];
  __syncthreads();

  const int tg = t >> 4;          // 0..15
  const int tf = (t & 15) << 2;   // f base
  float acc[4][4] = {};
#pragma unroll
  for (int k4 = 0; k4 < 32; ++k4) {
    float4 hv[4];
#pragma unroll
    for (int i = 0; i < 4; ++i)
      hv[i] = *(const float4*)&h_s[i * 16 + tg][k4 * 4];
#pragma unroll
    for (int kk = 0; kk < 4; ++kk) {
      float4 wv = *(const float4*)&W_s[k4 * 4 + kk][tf];
#pragma unroll
      for (int i = 0; i < 4; ++i) {
        float hx = ((const float*)&hv[i])[kk];
        acc[i][0] = fmaf(hx, wv.x, acc[i][0]);
        acc[i][1] = fmaf(hx, wv.y, acc[i][1]);
        acc[i][2] = fmaf(hx, wv.z, acc[i][2]);
        acc[i][3] = fmaf(hx, wv.w, acc[i][3]);
      }
    }
  }
#pragma unroll
  for (int i = 0; i < 4; ++i)
#pragma unroll
    for (int j = 0; j < 4; ++j)
      wt_s[tf + j][i * 16 + tg] = acc[i][j];
  __syncthreads();

  if (t < 64) {   // s1/s2 for row r = t (f32 exact)
    float v1 = 0.f, v2 = 0.f;
#pragma unroll 8
    for (int f = 0; f < 64; ++f) {
      float w = wt_s[f][t];
      v1 = fmaf(w, a_s[f], v1);
      v2 = fmaf(w, a_s[64 + f], v2);
    }
    s1g[b * 2048 + r0 + t] = v1;
    s2g[b * 2048 + r0 + t] = v2;
  }
  {  // WhT bf16 write, [b][f][j]
    int f = t >> 2, rb = (t & 3) << 4;
    unsigned short pk[16];
#pragma unroll
    for (int i = 0; i < 16; ++i) pk[i] = f2bf(wt_s[f][rb + i]);
    size_t base = ((size_t)(b * 64 + f)) * 2048 + r0 + rb;
    *(uint4*)&WhT[base]     = *(uint4*)&pk[0];
    *(uint4*)&WhT[base + 8] = *(uint4*)&pk[8];
  }
}

// ---------------- k12: fused stats + attention write + PV MFMA + ELU ----------------
// 16 rows per block. Pass 1: stream adj (nt), per-lane 16-bit masks -> LDS,
// denominator sum = sum(exp(lrelu(s1+s2))) (no max subtraction; range-safe).
// Pass 2: recompute e, write att (nt f32), bf16 MFMA PV, ELU epilogue.
__global__ __launch_bounds__(256, 4)
void k12_main(const int* __restrict__ adj, const unsigned short* __restrict__ WhT,
              const float* __restrict__ s1g, const float* __restrict__ s2g,
              float* __restrict__ hout, float* __restrict__ att)
{
  __shared__ float z_s[2048];                 // s2 row for this batch: 8 KB
  __shared__ unsigned short mask_s[16][128];  // bit j&15 of halfword j>>4: 4 KB
  __shared__ unsigned short wh_s[64][136];    // bf16 Wh tile [f][k]
  __shared__ unsigned short att_s[16][136];   // bf16 att tile

  const int t = threadIdx.x;
  const int b = blockIdx.y;
  const int r0 = blockIdx.x * 16;
  const size_t rowb = (size_t)(b * 2048 + r0);
  const int r = t >> 4;        // row 0..15 (one 16-lane group per row)
  const int q = t & 15;

  // stage s2 row (2048 f32)
  *(float4*)&z_s[t * 8]     = *(const float4*)&s2g[b * 2048 + t * 8];
  *(float4*)&z_s[t * 8 + 4] = *(const float4*)&s2g[b * 2048 + t * 8 + 4];
  __syncthreads();

  const float s1v = s1g[rowb + r];
  const int* __restrict__ arow = adj + (rowb + r) * 2048;

  // ---- pass 1: masks + denominator ----
  float sum = 0.f;
#pragma unroll
  for (int c = 0; c < 8; ++c) {
    const int jb = c * 256 + q * 16;
    i32x4 a0 = __builtin_nontemporal_load((const i32x4*)&arow[jb]);
    i32x4 a1 = __builtin_nontemporal_load((const i32x4*)&arow[jb + 4]);
    i32x4 a2 = __builtin_nontemporal_load((const i32x4*)&arow[jb + 8]);
    i32x4 a3 = __builtin_nontemporal_load((const i32x4*)&arow[jb + 12]);
    const float4 z0 = *(const float4*)&z_s[jb];
    const float4 z1 = *(const float4*)&z_s[jb + 4];
    const float4 z2 = *(const float4*)&z_s[jb + 8];
    const float4 z3 = *(const float4*)&z_s[jb + 12];
    unsigned bits = 0;
#define P1(av, zz, k)                                            \
    { bool p = (av) > 0;                                         \
      bits |= (unsigned)p << (k);                                \
      sum += p ? __expf(lrelu(s1v + (zz))) : 0.f; }
    P1(a0.x, z0.x, 0)  P1(a0.y, z0.y, 1)  P1(a0.z, z0.z, 2)  P1(a0.w, z0.w, 3)
    P1(a1.x, z1.x, 4)  P1(a1.y, z1.y, 5)  P1(a1.z, z1.z, 6)  P1(a1.w, z1.w, 7)
    P1(a2.x, z2.x, 8)  P1(a2.y, z2.y, 9)  P1(a2.z, z2.z, 10) P1(a2.w, z2.w, 11)
    P1(a3.x, z3.x, 12) P1(a3.y, z3.y, 13) P1(a3.z, z3.z, 14) P1(a3.w, z3.w, 15)
#undef P1
    mask_s[r][c * 16 + q] = (unsigned short)bits;
  }
  // 16-lane row reduction (lanes 0..15 of each group = one row)
#pragma unroll
  for (int o = 1; o < 16; o <<= 1) sum += __shfl_xor(sum, o);
  const float il = (sum > 0.f) ? 1.f / sum : -1.f;  // -1 sentinel: no neighbors
  const bool uni = (il < 0.f);
  __syncthreads();   // mask_s visible

  // ---- pass 2: att write + PV ----
  const int w  = t >> 6, l = t & 63;
  const int ln = l & 15, lg = l >> 4;
  const int ff = t >> 4, ko = q * 8;      // staging coords
  f32x4 acc = {0.f, 0.f, 0.f, 0.f};

  for (int j0 = 0; j0 < 2048; j0 += 128) {
    // T14: issue WhT loads early, LDS-write late
    uint4 wreg[4];
#pragma unroll
    for (int v = 0; v < 4; ++v)
      wreg[v] = *(const uint4*)&WhT[((size_t)(b * 64 + v * 16 + ff)) * 2048 + j0 + ko];

    // attention: 8 elems at j = j0 + q*8 for row r
    const int j = j0 + q * 8;
    unsigned mb = mask_s[r][j >> 4];
    mb >>= (j & 8);
    const float4 za = *(const float4*)&z_s[j];
    const float4 zb = *(const float4*)&z_s[j + 4];
    float4 oa, ob;
#define P2(dst, zz, k)                                             \
    { float e = __expf(lrelu(s1v + (zz))) * il;                    \
      dst = uni ? INV_N : (((mb >> (k)) & 1u) ? e : 0.f); }
    P2(oa.x, za.x, 0) P2(oa.y, za.y, 1) P2(oa.z, za.z, 2) P2(oa.w, za.w, 3)
    P2(ob.x, zb.x, 4) P2(ob.y, zb.y, 5) P2(ob.z, zb.z, 6) P2(ob.w, zb.w, 7)
#undef P2
    {
      union { float4 f; f32x4 v; } ua, ub; ua.f = oa; ub.f = ob;
      __builtin_nontemporal_store(ua.v, (f32x4*)&att[(rowb + r) * 2048 + j]);
      __builtin_nontemporal_store(ub.v, (f32x4*)&att[(rowb + r) * 2048 + j + 4]);
    }
    {
      us8 pk;
      pk[0] = f2bf(oa.x); pk[1] = f2bf(oa.y); pk[2] = f2bf(oa.z); pk[3] = f2bf(oa.w);
      pk[4] = f2bf(ob.x); pk[5] = f2bf(ob.y); pk[6] = f2bf(ob.z); pk[7] = f2bf(ob.w);
      *(us8*)&att_s[r][q * 8] = pk;
    }
#pragma unroll
    for (int v = 0; v < 4; ++v)
      *(uint4*)&wh_s[v * 16 + ff][ko] = wreg[v];

    lgkm_barrier();   // publish att_s + wh_s; nt att stores stay in flight
#pragma unroll
    for (int ks = 0; ks < 4; ++ks) {
      bf16x8 af = as_bf16(*(const us8*)&att_s[ln][ks * 32 + lg * 8]);
      bf16x8 bf = as_bf16(*(const us8*)&wh_s[w * 16 + ln][ks * 32 + lg * 8]);
      acc = __builtin_amdgcn_mfma_f32_16x16x32_bf16(af, bf, acc, 0, 0, 0);
    }
    lgkm_barrier();   // LDS reads done before next overwrite
  }

  // epilogue: ELU. C/D layout: col(N=f)=lane&15, row(M)=4*(lane>>4)+reg
#pragma unroll
  for (int q4 = 0; q4 < 4; ++q4) {
    const int rr = lg * 4 + q4;
    const float x = acc[q4];
    hout[(rowb + rr) * 64 + w * 16 + ln] = (x > 0.f) ? x : expm1f(x);
  }
}

extern "C" void kernel_launch(void* const* d_in, const int* in_sizes, int n_in,
                              void* d_out, int out_size, void* d_ws, size_t ws_size,
                              hipStream_t stream)
{
  const float* h   = (const float*)d_in[0];
  const int*   adj = (const int*)d_in[1];
  const float* W   = (const float*)d_in[2];
  const float* a   = (const float*)d_in[3];
  float* hout = (float*)d_out;
  float* att  = hout + (size_t)8 * 2048 * 64;

  char* ws = (char*)d_ws;
  unsigned short* WhT = (unsigned short*)ws;                    // 2 MB
  float* s1 = (float*)(ws + (size_t)(2u << 20));                // 64 KB each
  float* s2 = s1 + 16384;

  k0_wh   <<<dim3(32, 8),  256, 0, stream>>>(h, W, a, WhT, s1, s2);
  k12_main<<<dim3(128, 8), 256, 0, stream>>>(adj, WhT, s1, s2, hout, att);
}

// Round 4
// 91.518 us; speedup vs baseline: 1.1041x; 1.1041x over previous
//
#include <hip/hip_runtime.h>

#define GAT_ALPHA 0.2f
#define INV_N (1.0f / 2048.0f)

typedef float f32x4 __attribute__((ext_vector_type(4)));
typedef int   i32x4 __attribute__((ext_vector_type(4)));
typedef __bf16 bf16x8 __attribute__((ext_vector_type(8)));
typedef unsigned short us8 __attribute__((ext_vector_type(8)));

__device__ __forceinline__ unsigned short f2bf(float x) {
  union { float f; unsigned u; } v; v.f = x;
  unsigned r = v.u + 0x7FFFu + ((v.u >> 16) & 1u);   // RNE
  return (unsigned short)(r >> 16);
}
__device__ __forceinline__ float lrelu(float x) {
  return fmaxf(x, 0.f) + GAT_ALPHA * fminf(x, 0.f);
}

// ---------------- k0: Wh = h @ W (f32), s1/s2, WhT in bf16 [b][f][j] ----------------
__global__ __launch_bounds__(256)
void k0_wh(const float* __restrict__ h, const float* __restrict__ W,
           const float* __restrict__ a, unsigned short* __restrict__ WhT,
           float* __restrict__ s1g, float* __restrict__ s2g)
{
  __shared__ float h_s[64][132];
  __shared__ float W_s[128][64];
  __shared__ float wt_s[64][66];
  __shared__ float a_s[128];
  const int t = threadIdx.x;
  const int b = blockIdx.y;
  const int r0 = blockIdx.x * 64;

#pragma unroll
  for (int v = 0; v < 8; ++v) {
    int c = v * 256 + t;
    int k = c >> 4, fo = (c & 15) << 2;
    *(float4*)&W_s[k][fo] = *(const float4*)&W[k * 64 + fo];
  }
#pragma unroll
  for (int v = 0; v < 8; ++v) {
    int c = v * 256 + t;
    int r = c >> 5, ko = (c & 31) << 2;
    *(float4*)&h_s[r][ko] = *(const float4*)&h[((size_t)(b * 2048 + r0 + r)) * 128 + ko];
  }
  if (t < 128) a_s[t] = a[t];
  __syncthreads();

  const int tg = t >> 4;          // 0..15
  const int tf = (t & 15) << 2;   // f base
  float acc[4][4] = {};
#pragma unroll
  for (int k4 = 0; k4 < 32; ++k4) {
    float4 hv[4];
#pragma unroll
    for (int i = 0; i < 4; ++i)
      hv[i] = *(const float4*)&h_s[i * 16 + tg][k4 * 4];
#pragma unroll
    for (int kk = 0; kk < 4; ++kk) {
      float4 wv = *(const float4*)&W_s[k4 * 4 + kk][tf];
#pragma unroll
      for (int i = 0; i < 4; ++i) {
        float hx = ((const float*)&hv[i])[kk];
        acc[i][0] = fmaf(hx, wv.x, acc[i][0]);
        acc[i][1] = fmaf(hx, wv.y, acc[i][1]);
        acc[i][2] = fmaf(hx, wv.z, acc[i][2]);
        acc[i][3] = fmaf(hx, wv.w, acc[i][3]);
      }
    }
  }
#pragma unroll
  for (int i = 0; i < 4; ++i)
#pragma unroll
    for (int j = 0; j < 4; ++j)
      wt_s[tf + j][i * 16 + tg] = acc[i][j];
  __syncthreads();

  if (t < 64) {   // s1/s2 for row r = t (f32 exact)
    float v1 = 0.f, v2 = 0.f;
#pragma unroll 8
    for (int f = 0; f < 64; ++f) {
      float w = wt_s[f][t];
      v1 = fmaf(w, a_s[f], v1);
      v2 = fmaf(w, a_s[64 + f], v2);
    }
    s1g[b * 2048 + r0 + t] = v1;
    s2g[b * 2048 + r0 + t] = v2;
  }
  {  // WhT bf16 write, [b][f][j]
    int f = t >> 2, rb = (t & 3) << 4;
    unsigned short pk[16];
#pragma unroll
    for (int i = 0; i < 16; ++i) pk[i] = f2bf(wt_s[f][rb + i]);
    size_t base = ((size_t)(b * 64 + f)) * 2048 + r0 + rb;
    *(uint4*)&WhT[base]     = *(uint4*)&pk[0];
    *(uint4*)&WhT[base + 8] = *(uint4*)&pk[8];
  }
}

// ---------------- k1: wave-per-row: denom l + bitmask (ballot); no max pass ----------------
// bit convention: word[c*4 + q] bit l  <->  j = c*256 + 4*l + q
__global__ __launch_bounds__(256)
void k1_stats(const int* __restrict__ adj, const float* __restrict__ s1g,
              const float* __restrict__ s2g, float* __restrict__ lrow,
              unsigned long long* __restrict__ gmask)
{
  const int t = threadIdx.x;
  const int l = t & 63, w = t >> 6;
  const int b = blockIdx.y;
  const int i = blockIdx.x * 4 + w;
  const size_t row = (size_t)(b * 2048 + i);
  const int* __restrict__ arow = adj + row * 2048;
  const float* __restrict__ z = s2g + b * 2048;
  unsigned long long* __restrict__ g = gmask + row * 32;

  float4 zv[8];
  unsigned pb = 0;           // 4 pred bits per chunk, 8 chunks
#pragma unroll
  for (int c = 0; c < 8; ++c) {
    i32x4 av = __builtin_nontemporal_load((const i32x4*)&arow[c * 256 + 4 * l]);
    zv[c] = *(const float4*)&z[c * 256 + 4 * l];
    const bool p0 = av.x > 0, p1 = av.y > 0, p2 = av.z > 0, p3 = av.w > 0;
    unsigned long long b0 = __ballot(p0), b1 = __ballot(p1);
    unsigned long long b2 = __ballot(p2), b3 = __ballot(p3);
    if (l == 0) {
      ulonglong2 u0; u0.x = b0; u0.y = b1;
      ulonglong2 u1; u1.x = b2; u1.y = b3;
      *(ulonglong2*)&g[c * 4]     = u0;
      *(ulonglong2*)&g[c * 4 + 2] = u1;
    }
    pb |= (unsigned(p0) | (unsigned(p1) << 1) | (unsigned(p2) << 2) | (unsigned(p3) << 3)) << (c * 4);
  }

  const float s1v = s1g[row];
  float sum = 0.f;
#pragma unroll
  for (int c = 0; c < 8; ++c) {
    sum += ((pb >> (c * 4)) & 1u) ? __expf(lrelu(s1v + zv[c].x)) : 0.f;
    sum += ((pb >> (c * 4 + 1)) & 1u) ? __expf(lrelu(s1v + zv[c].y)) : 0.f;
    sum += ((pb >> (c * 4 + 2)) & 1u) ? __expf(lrelu(s1v + zv[c].z)) : 0.f;
    sum += ((pb >> (c * 4 + 3)) & 1u) ? __expf(lrelu(s1v + zv[c].w)) : 0.f;
  }
#pragma unroll
  for (int o = 32; o > 0; o >>= 1) sum += __shfl_xor(sum, o);

  if (l == 0) lrow[row] = sum;
}

// ---------------- k2: barrier-free att write + PV MFMA + ELU ----------------
// 32 rows/block, 4 waves. Wave w: row-tile rt=(w&1)*16, f-tiles 2*(w>>1), +1.
// Each lane computes ITS OWN MFMA A-fragment in registers:
//   row = rt + (l&15), j = j0 + ks*32 + (l>>4)*8 + m   (m = 0..7)
// B-fragment loads straight from L2-resident WhT. No LDS tiles, no loop barriers.
__global__ __launch_bounds__(256)
void k2_att_pv(const unsigned long long* __restrict__ gmask,
               const unsigned short* __restrict__ WhT,
               const float* __restrict__ s1g, const float* __restrict__ s2g,
               const float* __restrict__ lrow,
               float* __restrict__ hout, float* __restrict__ att)
{
  __shared__ float z_s[2048];
  __shared__ float s1_s[32], il_s[32];

  const int t = threadIdx.x;
  const int b = blockIdx.y;
  const int r0 = blockIdx.x * 32;
  const size_t rowb = (size_t)(b * 2048 + r0);

  *(float4*)&z_s[t * 8]     = *(const float4*)&s2g[b * 2048 + t * 8];
  *(float4*)&z_s[t * 8 + 4] = *(const float4*)&s2g[b * 2048 + t * 8 + 4];
  if (t < 32) {
    float L = lrow[rowb + t];
    s1_s[t] = s1g[rowb + t];
    il_s[t] = (L > 0.f) ? 1.f / L : -1.f;   // -1 sentinel: no neighbors -> uniform 1/N
  }
  __syncthreads();

  const int w  = t >> 6, l = t & 63;
  const int ln = l & 15, lg = l >> 4;
  const int rt = (w & 1) << 4;
  const int fp = w >> 1;                    // f-tile pair: tiles 2fp, 2fp+1
  const int row = rt + ln;
  const bool writer = (w < 2);

  const float s1v = s1_s[row];
  const float il  = il_s[row];
  const bool uni  = (il < 0.f);
  const unsigned long long* __restrict__ gm = gmask + (rowb + row) * 32;
  const unsigned short* __restrict__ wb0 = WhT + ((size_t)(b * 64 + 2 * fp * 16 + ln)) * 2048;
  const unsigned short* __restrict__ wb1 = wb0 + 16 * 2048;
  float* __restrict__ arow = att + (rowb + row) * 2048;

  f32x4 acc0 = {0.f, 0.f, 0.f, 0.f};
  f32x4 acc1 = {0.f, 0.f, 0.f, 0.f};

  unsigned long long w0 = 0, w1 = 0, w2 = 0, w3 = 0;
  for (int j0 = 0; j0 < 2048; j0 += 128) {
    if ((j0 & 255) == 0) {   // refresh ballot words for 256-j chunk
      const int c = j0 >> 8;
      ulonglong2 u0 = *(const ulonglong2*)&gm[c * 4];
      ulonglong2 u1 = *(const ulonglong2*)&gm[c * 4 + 2];
      w0 = u0.x; w1 = u0.y; w2 = u1.x; w3 = u1.y;
    }
#pragma unroll
    for (int ks = 0; ks < 4; ++ks) {
      const int jb = j0 + ks * 32 + lg * 8;
      const int pos0 = (jb & 255) >> 2;     // base bit position, never wraps
      const float4 za = *(const float4*)&z_s[jb];
      const float4 zb = *(const float4*)&z_s[jb + 4];
      float o[8];
#define PE(dst, zz, m)                                                     \
      { float e = __expf(lrelu(s1v + (zz))) * il;                          \
        const unsigned long long wq = ((m) & 3) == 0 ? w0 :                \
                                      ((m) & 3) == 1 ? w1 :                \
                                      ((m) & 3) == 2 ? w2 : w3;            \
        const bool on = ((wq >> (pos0 + ((m) >> 2))) & 1ull) != 0;         \
        dst = uni ? INV_N : (on ? e : 0.f); }
      PE(o[0], za.x, 0) PE(o[1], za.y, 1) PE(o[2], za.z, 2) PE(o[3], za.w, 3)
      PE(o[4], zb.x, 4) PE(o[5], zb.y, 5) PE(o[6], zb.z, 6) PE(o[7], zb.w, 7)
#undef PE
      if (writer) {
        f32x4 sa = {o[0], o[1], o[2], o[3]};
        f32x4 sb = {o[4], o[5], o[6], o[7]};
        __builtin_nontemporal_store(sa, (f32x4*)&arow[jb]);
        __builtin_nontemporal_store(sb, (f32x4*)&arow[jb + 4]);
      }
      bf16x8 af;
#pragma unroll
      for (int m = 0; m < 8; ++m) af[m] = (__bf16)o[m];
      union { us8 u; bf16x8 v; } b0c, b1c;
      b0c.u = *(const us8*)&wb0[jb];
      b1c.u = *(const us8*)&wb1[jb];
      acc0 = __builtin_amdgcn_mfma_f32_16x16x32_bf16(af, b0c.v, acc0, 0, 0, 0);
      acc1 = __builtin_amdgcn_mfma_f32_16x16x32_bf16(af, b1c.v, acc1, 0, 0, 0);
    }
  }

  // epilogue: ELU. C/D layout: col(N=f)=lane&15, row(M)=4*(lane>>4)+reg
#pragma unroll
  for (int q = 0; q < 4; ++q) {
    const int rr = rt + lg * 4 + q;
    {
      float x = acc0[q];
      hout[(rowb + rr) * 64 + (2 * fp) * 16 + ln] = (x > 0.f) ? x : expm1f(x);
    }
    {
      float x = acc1[q];
      hout[(rowb + rr) * 64 + (2 * fp + 1) * 16 + ln] = (x > 0.f) ? x : expm1f(x);
    }
  }
}

extern "C" void kernel_launch(void* const* d_in, const int* in_sizes, int n_in,
                              void* d_out, int out_size, void* d_ws, size_t ws_size,
                              hipStream_t stream)
{
  const float* h   = (const float*)d_in[0];
  const int*   adj = (const int*)d_in[1];
  const float* W   = (const float*)d_in[2];
  const float* a   = (const float*)d_in[3];
  float* hout = (float*)d_out;
  float* att  = hout + (size_t)8 * 2048 * 64;

  char* ws = (char*)d_ws;
  unsigned short* WhT = (unsigned short*)ws;                    // 2 MB
  float* s1 = (float*)(ws + (size_t)(2u << 20));                // 64 KB each
  float* s2 = s1 + 16384;
  float* lr = s2 + 16384;
  unsigned long long* gmask =
      (unsigned long long*)(ws + (size_t)(2u << 20) + 3 * 65536); // 4 MB

  k0_wh    <<<dim3(32, 8),  256, 0, stream>>>(h, W, a, WhT, s1, s2);
  k1_stats <<<dim3(512, 8), 256, 0, stream>>>(adj, s1, s2, lr, gmask);
  k2_att_pv<<<dim3(64, 8),  256, 0, stream>>>(gmask, WhT, s1, s2, lr, hout, att);
}